// Round 7
// baseline (1881.043 us; speedup 1.0000x reference)
//
#include <hip/hip_runtime.h>
#include <cstdint>

#define BB   4096
#define TT   7
#define INF  512
#define HH   1024
#define OUTF 512
#define G3   3072   // 3*H

typedef short bf16x8 __attribute__((ext_vector_type(8)));
typedef float f32x4  __attribute__((ext_vector_type(4)));

static __device__ __forceinline__ unsigned short f2bf(float f) {
  unsigned u = __float_as_uint(f);
  unsigned r = ((u >> 16) & 1u) + 0x7FFFu;   // RNE
  return (unsigned short)((u + r) >> 16);
}
static __device__ __forceinline__ float bf2f(unsigned short s) {
  return __uint_as_float(((unsigned)s) << 16);
}

#define GLDS16(gp, lp)                                                        \
  __builtin_amdgcn_global_load_lds(                                           \
      (const __attribute__((address_space(1))) void*)(gp),                    \
      (__attribute__((address_space(3))) void*)(lp), 16, 0, 0)

__device__ __forceinline__ int xcd_swz(int bid, int nwg) {
  return (bid & 7) * (nwg >> 3) + (bid >> 3);   // bijective: nwg % 8 == 0
}

__global__ __launch_bounds__(256)
void cvt_f32_to_bf16_x4(const float* __restrict__ in, unsigned short* __restrict__ out, int n4) {
  int i = blockIdx.x * 256 + threadIdx.x;
  if (i >= n4) return;
  const float4 v = ((const float4*)in)[i];
  ushort4 o;
  o.x = f2bf(v.x); o.y = f2bf(v.y); o.z = f2bf(v.z); o.w = f2bf(v.w);
  ((ushort4*)out)[i] = o;
}

// ---------------------------------------------------------------------------
// GEMM core (round-2 proven structure): C[M,N] = A[M,K] @ W[N,K]^T + bias.
// BK=32, SINGLE-buffered, 16 KB LDS (linear [rows][32]) -> ~5 blocks/CU.
// On this problem (short K, many small GEMMs) occupancy/TLP hides staging
// latency better than intra-block dbuf (r4/r5/r6 all regressed vs this).
// mode: 0 = f32 store; 1 = f32 tanh; 2 = f32 tanh + add[]; 3 = bf16 store.
// NOTE: exactly ONE gemm_core call per kernel (single __shared__ instance).
// ---------------------------------------------------------------------------
template<int BM, int BN, int WM, int WN, int GN>
__device__ __forceinline__ void gemm_core(
    const unsigned short* __restrict__ A, long lda, long bm,
    const unsigned short* __restrict__ Wp, long ldw, int K,
    const float* __restrict__ biasp,
    void* __restrict__ Cp, long ldc,
    const float* __restrict__ addp, long ldadd, int mode)
{
  constexpr int AR = (BM * 4) / 256;   // 16B chunks per buffer / 256 threads
  constexpr int WR = (BN * 4) / 256;
  __shared__ __attribute__((aligned(16))) unsigned short sm[(BM + BN) * 32];
  unsigned short* As = sm;
  unsigned short* Ws = sm + BM * 32;
  __attribute__((address_space(3))) unsigned short* lAs =
      (__attribute__((address_space(3))) unsigned short*)As;
  __attribute__((address_space(3))) unsigned short* lWs =
      (__attribute__((address_space(3))) unsigned short*)Ws;

  const int tid  = threadIdx.x;
  const int lane = tid & 63;
  const int wid  = tid >> 6;
  const int wr = (wid / GN) * (WM * 16);
  const int wc = (wid % GN) * (WN * 16);
  const int fr = lane & 15;
  const int fk = (lane >> 4) * 8;      // 8 contiguous bf16 (16B) k-chunk

  const unsigned short* gpa[AR];
  const unsigned short* gpw[WR];
  int lofa[AR], lofw[WR];
#pragma unroll
  for (int r = 0; r < AR; ++r) {
    const int id = r * 256 + tid;
    gpa[r] = A + (bm + (id >> 2)) * lda + (id & 3) * 8;
    lofa[r] = id * 8;
  }
#pragma unroll
  for (int r = 0; r < WR; ++r) {
    const int id = r * 256 + tid;
    gpw[r] = Wp + (long)(id >> 2) * ldw + (id & 3) * 8;
    lofw[r] = id * 8;
  }

  f32x4 acc[WM][WN] = {};
  for (int kt = 0; kt < K; kt += 32) {
    if (kt) __syncthreads();          // prior reads done before overwrite
#pragma unroll
    for (int r = 0; r < AR; ++r) GLDS16(gpa[r] + kt, lAs + lofa[r]);
#pragma unroll
    for (int r = 0; r < WR; ++r) GLDS16(gpw[r] + kt, lWs + lofw[r]);
    __syncthreads();                  // compiler drains vmcnt before s_barrier

    bf16x8 af[WM], wf[WN];
#pragma unroll
    for (int i = 0; i < WM; ++i)
      af[i] = *(const bf16x8*)&As[(wr + i * 16 + fr) * 32 + fk];
#pragma unroll
    for (int i = 0; i < WN; ++i)
      wf[i] = *(const bf16x8*)&Ws[(wc + i * 16 + fr) * 32 + fk];
#pragma unroll
    for (int mi = 0; mi < WM; ++mi)
#pragma unroll
      for (int ni = 0; ni < WN; ++ni)
        acc[mi][ni] = __builtin_amdgcn_mfma_f32_16x16x32_bf16(af[mi], wf[ni], acc[mi][ni], 0, 0, 0);
  }

  const int q = lane >> 4;
#pragma unroll
  for (int ni = 0; ni < WN; ++ni) {
    const int col = wc + ni * 16 + fr;
    const float bv = biasp[col];
#pragma unroll
    for (int mi = 0; mi < WM; ++mi) {
      const long row = bm + wr + mi * 16 + q * 4;
#pragma unroll
      for (int j = 0; j < 4; ++j) {
        const float v = acc[mi][ni][j] + bv;
        if (mode == 0)      ((float*)Cp)[(row + j) * ldc + col] = v;
        else if (mode == 1) ((float*)Cp)[(row + j) * ldc + col] = tanhf(v);
        else if (mode == 2) ((float*)Cp)[(row + j) * ldc + col] = tanhf(v) + addp[(row + j) * ldadd + col];
        else                ((unsigned short*)Cp)[(row + j) * ldc + col] = f2bf(v);
      }
    }
  }
}

// ---------------------------------------------------------------------------
// D1 mega-dispatch: all GEMMs that depend only on state (t-1):
//   [0,768)    gi1  = x_t @ Wih1^T          (bf16, K=512)
//   [768,2304) gh1/gh2 = h1/h2 @ Whh^T      (bf16, K=1024)
//   [2304,2432) out(t-1) = tanh(h2@Wo2^T+bo2) + o1t(t-1)   (only when t>0)
// ---------------------------------------------------------------------------
__global__ __launch_bounds__(256)
void k_step1(const unsigned short* __restrict__ xb_t,
             const unsigned short* __restrict__ wih1b, const float* __restrict__ bih1,
             unsigned short* __restrict__ gi1b,
             const unsigned short* __restrict__ h1b, const unsigned short* __restrict__ h2b,
             const unsigned short* __restrict__ whh1b, const unsigned short* __restrict__ whh2b,
             const float* __restrict__ bhh1, const float* __restrict__ bhh2,
             unsigned short* __restrict__ gh1, unsigned short* __restrict__ gh2,
             const unsigned short* __restrict__ wo2b, const float* __restrict__ bo2,
             const float* __restrict__ o1t_prev, float* __restrict__ out_prev)
{
  const int wg = xcd_swz(blockIdx.x, gridDim.x);
  const unsigned short* A; long lda; long bm;
  const unsigned short* W; long ldw; int K;
  const float* bias; void* C; long ldc; int mode;
  const float* addp = nullptr; long ldadd = 0;
  if (wg < 768) {                       // gi1
    const int bx = wg & 31, by = wg >> 5;
    A = xb_t; lda = (long)TT * INF; bm = (long)bx * 128;
    W = wih1b + (long)by * 128 * INF; ldw = INF; K = INF;
    bias = bih1 + by * 128; C = gi1b + by * 128; ldc = G3; mode = 3;
  } else if (wg < 2304) {               // gh1 / gh2
    int idx = wg - 768;
    const int z = idx >= 768;
    if (z) idx -= 768;
    const int bx = idx & 31, by = idx >> 5;
    A = z ? h2b : h1b; lda = HH; bm = (long)bx * 128;
    W = (z ? whh2b : whh1b) + (long)by * 128 * HH; ldw = HH; K = HH;
    bias = (z ? bhh2 : bhh1) + by * 128;
    C = (z ? gh2 : gh1) + by * 128; ldc = G3; mode = 3;
  } else {                              // o2 -> d_out row t-1
    const int idx = wg - 2304;
    const int bx = idx & 31, by = idx >> 5;   // by 0..3
    A = h2b; lda = HH; bm = (long)bx * 128;
    W = wo2b + (long)by * 128 * HH; ldw = HH; K = HH;
    bias = bo2 + by * 128;
    C = out_prev + by * 128; ldc = (long)TT * OUTF; mode = 2;
    addp = o1t_prev + by * 128; ldadd = OUTF;
  }
  gemm_core<128,128,4,4,2>(A, lda, bm, W, ldw, K, bias, C, ldc, addp, ldadd, mode);
}

// D2: gi2 = h1 @ Wih2^T (bf16) | o1t = tanh(h1 @ Wo1^T + bo1) (f32). 896 blocks.
__global__ __launch_bounds__(256)
void k_gi2_o1(const unsigned short* __restrict__ h1b,
              const unsigned short* __restrict__ Wih2, const float* __restrict__ bih2,
              unsigned short* __restrict__ gi2,
              const unsigned short* __restrict__ Wo1, const float* __restrict__ bo1,
              float* __restrict__ o1t)
{
  const int wg = xcd_swz(blockIdx.x, gridDim.x);   // 896
  const int bx = wg & 31;
  const int by = wg >> 5;
  const bool g = (by < 24);
  const int bo = by - 24;
  const unsigned short* Ww = g ? (Wih2 + (long)by * 128 * HH) : (Wo1 + (long)bo * 128 * HH);
  const float* bias        = g ? (bih2 + by * 128)            : (bo1 + bo * 128);
  void* C                  = g ? (void*)(gi2 + by * 128)      : (void*)(o1t + bo * 128);
  const long ldc           = g ? (long)G3 : (long)OUTF;
  gemm_core<128,128,4,4,2>(h1b, HH, (long)bx * 128, Ww, HH, HH, bias, C, ldc,
                           nullptr, 0, g ? 3 : 1);
}

// final step's output head (128 blocks)
__global__ __launch_bounds__(256)
void k_o2f(const unsigned short* __restrict__ h2b,
           const unsigned short* __restrict__ Wo2, const float* __restrict__ bo2,
           const float* __restrict__ o1t, float* __restrict__ outp)
{
  const int wg = xcd_swz(blockIdx.x, gridDim.x);   // 128
  const int bx = wg & 31;
  const int by = wg >> 5;
  gemm_core<128,128,4,4,2>(h2b, HH, (long)bx * 128, Wo2 + (long)by * 128 * HH, HH, HH,
                           bo2 + by * 128, outp + by * 128, (long)TT * OUTF,
                           o1t + by * 128, OUTF, 2);
}

// GRU gate: h = (1-z)*n + z*h_old. gi, gh bf16; recurrence on bf16 hb.
__global__ __launch_bounds__(256)
void k_gate(const unsigned short* __restrict__ gi, long gistride,
            const unsigned short* __restrict__ gh,
            unsigned short* __restrict__ hb,
            float* __restrict__ auxp)
{
  const int i4 = blockIdx.x * 256 + threadIdx.x;
  const int e  = i4 << 2;
  const int b = e >> 10;                  // H = 1024
  const int c = e & 1023;
  const unsigned short* g = gi + (long)b * gistride + c;
  const ushort4 a0 = *(const ushort4*)(g);
  const ushort4 a1 = *(const ushort4*)(g + HH);
  const ushort4 a2 = *(const ushort4*)(g + 2 * HH);
  const unsigned short* gg = gh + (long)b * G3 + c;
  const ushort4 b0 = *(const ushort4*)(gg);
  const ushort4 b1 = *(const ushort4*)(gg + HH);
  const ushort4 b2 = *(const ushort4*)(gg + 2 * HH);
  const f32x4 ir  = f32x4{bf2f(a0.x), bf2f(a0.y), bf2f(a0.z), bf2f(a0.w)};
  const f32x4 iz  = f32x4{bf2f(a1.x), bf2f(a1.y), bf2f(a1.z), bf2f(a1.w)};
  const f32x4 inn = f32x4{bf2f(a2.x), bf2f(a2.y), bf2f(a2.z), bf2f(a2.w)};
  const f32x4 hr  = f32x4{bf2f(b0.x), bf2f(b0.y), bf2f(b0.z), bf2f(b0.w)};
  const f32x4 hz  = f32x4{bf2f(b1.x), bf2f(b1.y), bf2f(b1.z), bf2f(b1.w)};
  const f32x4 hn  = f32x4{bf2f(b2.x), bf2f(b2.y), bf2f(b2.z), bf2f(b2.w)};
  const ushort4 ho = *(const ushort4*)(hb + e);
  const f32x4 h = f32x4{bf2f(ho.x), bf2f(ho.y), bf2f(ho.z), bf2f(ho.w)};
  f32x4 hnew;
  float vsum = 0.f;
#pragma unroll
  for (int j = 0; j < 4; ++j) {
    const float r = 1.f / (1.f + __expf(-(ir[j] + hr[j])));
    const float z = 1.f / (1.f + __expf(-(iz[j] + hz[j])));
    const float n = tanhf(inn[j] + r * hn[j]);
    hnew[j] = (1.f - z) * n + z * h[j];
    vsum += hnew[j] * hnew[j];
  }
  ushort4 o;
  o.x = f2bf(hnew[0]); o.y = f2bf(hnew[1]); o.z = f2bf(hnew[2]); o.w = f2bf(hnew[3]);
  *(ushort4*)(hb + e) = o;
  if (auxp != nullptr) {
#pragma unroll
    for (int off = 32; off > 0; off >>= 1) vsum += __shfl_down(vsum, off);
    __shared__ float wsum[4];
    if ((threadIdx.x & 63) == 0) wsum[threadIdx.x >> 6] = vsum;
    __syncthreads();
    if (threadIdx.x == 0) auxp[blockIdx.x] = wsum[0] + wsum[1] + wsum[2] + wsum[3];
  }
}

__global__ __launch_bounds__(256)
void aux_reduce(const float* __restrict__ p, int n, float* __restrict__ out, float scale) {
  float s = 0.f;
  for (int i = threadIdx.x; i < n; i += 256) s += p[i];
#pragma unroll
  for (int off = 32; off > 0; off >>= 1) s += __shfl_down(s, off);
  __shared__ float wsum[4];
  if ((threadIdx.x & 63) == 0) wsum[threadIdx.x >> 6] = s;
  __syncthreads();
  if (threadIdx.x == 0) out[0] = (wsum[0] + wsum[1] + wsum[2] + wsum[3]) * scale;
}

extern "C" void kernel_launch(void* const* d_in, const int* in_sizes, int n_in,
                              void* d_out, int out_size, void* d_ws, size_t ws_size,
                              hipStream_t stream) {
  const float* x    = (const float*)d_in[0];
  const float* Wih1 = (const float*)d_in[1];
  const float* Whh1 = (const float*)d_in[2];
  const float* bih1 = (const float*)d_in[3];
  const float* bhh1 = (const float*)d_in[4];
  const float* Wih2 = (const float*)d_in[5];
  const float* Whh2 = (const float*)d_in[6];
  const float* bih2 = (const float*)d_in[7];
  const float* bhh2 = (const float*)d_in[8];
  const float* Wo1  = (const float*)d_in[9];
  const float* bo1  = (const float*)d_in[10];
  const float* Wo2  = (const float*)d_in[11];
  const float* bo2  = (const float*)d_in[12];

  char* ws = (char*)d_ws;
  size_t off = 0;
  auto alloc = [&](size_t bytes) {
    char* p = ws + off;
    off = (off + bytes + 255) & ~(size_t)255;
    return p;
  };

  unsigned short* xb    = (unsigned short*)alloc((size_t)BB * TT * INF * 2);
  unsigned short* wih1b = (unsigned short*)alloc((size_t)G3 * INF * 2);
  unsigned short* whh1b = (unsigned short*)alloc((size_t)G3 * HH * 2);
  unsigned short* wih2b = (unsigned short*)alloc((size_t)G3 * HH * 2);
  unsigned short* whh2b = (unsigned short*)alloc((size_t)G3 * HH * 2);
  unsigned short* wo1b  = (unsigned short*)alloc((size_t)OUTF * HH * 2);
  unsigned short* wo2b  = (unsigned short*)alloc((size_t)OUTF * HH * 2);
  unsigned short* h1b = (unsigned short*)alloc((size_t)BB * HH * 2);
  unsigned short* h2b = (unsigned short*)alloc((size_t)BB * HH * 2);
  unsigned short* gh1 = (unsigned short*)alloc((size_t)BB * G3 * 2);  // also gi2
  unsigned short* gh2 = (unsigned short*)alloc((size_t)BB * G3 * 2);
  unsigned short* gi1b = (unsigned short*)alloc((size_t)BB * G3 * 2);
  float* o1t  = (float*)alloc((size_t)BB * OUTF * 4);
  float* auxp = (float*)alloc((size_t)TT * (BB * HH / 1024) * 4);
  unsigned short* gi2 = gh1;          // gh1 dead after gate1; stream order safe

  float* aux = (float*)d_out + (size_t)BB * TT * OUTF;

  auto cvt = [&](const float* src, unsigned short* dst, size_t n) {
    int n4 = (int)(n / 4);
    cvt_f32_to_bf16_x4<<<dim3((n4 + 255) / 256), dim3(256), 0, stream>>>(src, dst, n4);
  };
  cvt(x,    xb,    (size_t)BB * TT * INF);
  cvt(Wih1, wih1b, (size_t)G3 * INF);
  cvt(Whh1, whh1b, (size_t)G3 * HH);
  cvt(Wih2, wih2b, (size_t)G3 * HH);
  cvt(Whh2, whh2b, (size_t)G3 * HH);
  cvt(Wo1,  wo1b,  (size_t)OUTF * HH);
  cvt(Wo2,  wo2b,  (size_t)OUTF * HH);

  hipMemsetAsync(h1b, 0, (size_t)BB * HH * 2, stream);
  hipMemsetAsync(h2b, 0, (size_t)BB * HH * 2, stream);

  const dim3 blk(256);
  const int gateGrid = BB * HH / 1024;   // 4096

  for (int t = 0; t < TT; ++t) {
    const int d1grid = (t == 0) ? 2304 : 2432;   // o2 segment only when t > 0
    k_step1<<<dim3(d1grid), blk, 0, stream>>>(
        xb + (size_t)t * INF, wih1b, bih1, gi1b,
        h1b, h2b, whh1b, whh2b, bhh1, bhh2, gh1, gh2,
        wo2b, bo2, o1t, (float*)d_out + (size_t)(t > 0 ? t - 1 : 0) * OUTF);
    k_gate<<<dim3(gateGrid), blk, 0, stream>>>(gi1b, (long)G3, gh1, h1b, nullptr);
    k_gi2_o1<<<dim3(32 * 28), blk, 0, stream>>>(h1b, wih2b, bih2, gi2, wo1b, bo1, o1t);
    k_gate<<<dim3(gateGrid), blk, 0, stream>>>(gi2, (long)G3, gh2, h2b,
                                               auxp + (size_t)t * gateGrid);
  }
  k_o2f<<<dim3(128), blk, 0, stream>>>(h2b, wo2b, bo2, o1t,
                                       (float*)d_out + (size_t)(TT - 1) * OUTF);
  aux_reduce<<<dim3(1), blk, 0, stream>>>(auxp, TT * gateGrid, aux,
                                          1.f / ((float)BB * (float)HH));
}

// Round 8
// 1659.902 us; speedup vs baseline: 1.1332x; 1.1332x over previous
//
#include <hip/hip_runtime.h>
#include <cstdint>

#define BB   4096
#define TT   7
#define INF  512
#define HH   1024
#define OUTF 512
#define G3   3072   // 3*H

typedef short bf16x8 __attribute__((ext_vector_type(8)));
typedef float f32x4  __attribute__((ext_vector_type(4)));

static __device__ __forceinline__ unsigned short f2bf(float f) {
  unsigned u = __float_as_uint(f);
  unsigned r = ((u >> 16) & 1u) + 0x7FFFu;   // RNE
  return (unsigned short)((u + r) >> 16);
}
static __device__ __forceinline__ float bf2f(unsigned short s) {
  return __uint_as_float(((unsigned)s) << 16);
}

#define GLDS16(gp, lp)                                                        \
  __builtin_amdgcn_global_load_lds(                                           \
      (const __attribute__((address_space(1))) void*)(gp),                    \
      (__attribute__((address_space(3))) void*)(lp), 16, 0, 0)

__device__ __forceinline__ int xcd_swz(int bid, int nwg) {
  return (bid & 7) * (nwg >> 3) + (bid >> 3);   // bijective: nwg % 8 == 0
}

__global__ __launch_bounds__(256)
void cvt_f32_to_bf16_x4(const float* __restrict__ in, unsigned short* __restrict__ out, int n4) {
  int i = blockIdx.x * 256 + threadIdx.x;
  if (i >= n4) return;
  const float4 v = ((const float4*)in)[i];
  ushort4 o;
  o.x = f2bf(v.x); o.y = f2bf(v.y); o.z = f2bf(v.z); o.w = f2bf(v.w);
  ((ushort4*)out)[i] = o;
}

// ---------------------------------------------------------------------------
// 256x256 GEMM core, 512 threads (8 waves, 2M x 4N -> 128x64 per-wave tile).
// Why: 64x64 wave tiles need 512 B LDS-read per MFMA (6 cy) > matrix pipe
// (4.85 cy) -> LDS-read-bound at ~11% MfmaUtil (r4-r7). 128x64 tiles reuse
// A-frags x4 and B-frags x8 -> 384 B/MFMA -> MFMA-bound.
// BK=64 double-buffered (128 KB LDS), STAGE(next) before compute, plain
// __syncthreads schedule (r6-verified safe). Chunk-XOR swizzle (r5-verified,
// 0 conflicts): LDS linear dest, global src chunk cc^(row&7), same on read.
// mode: 0 = f32 store; 1 = f32 tanh; 2 = f32 tanh + add[]; 3 = bf16 store.
// ---------------------------------------------------------------------------
__device__ __forceinline__ void gemm256_core(
    const unsigned short* __restrict__ A, long lda, long bm,
    const unsigned short* __restrict__ Wp, long ldw, int K,
    const float* __restrict__ biasp,
    void* __restrict__ Cp, long ldc,
    const float* __restrict__ addp, long ldadd, int mode)
{
  constexpr int TBUF = 256 * 64;       // ushorts per operand buffer (32 KB)
  __shared__ __attribute__((aligned(16))) unsigned short sm[4 * TBUF];  // 128 KB
  unsigned short* As = sm;             // [2][256][64]
  unsigned short* Ws = sm + 2 * TBUF;  // [2][256][64]
  __attribute__((address_space(3))) unsigned short* lAs =
      (__attribute__((address_space(3))) unsigned short*)As;
  __attribute__((address_space(3))) unsigned short* lWs =
      (__attribute__((address_space(3))) unsigned short*)Ws;

  const int tid  = threadIdx.x;        // 0..511
  const int lane = tid & 63;
  const int wid  = tid >> 6;
  const int wr = (wid >> 2) * 128;     // wave rows: 0 or 128
  const int wc = (wid & 3) * 64;       // wave cols: 0/64/128/192
  const int fr = lane & 15;
  const int q2 = lane >> 4;            // 0..3: 16B chunk within 32-wide K-slice

  // staging: 2048 chunks(16B) per operand, 4 per thread; id = r*512+tid;
  // row = id>>3, cc = id&7; LDS dest linear, global chunk cc^(row&7).
  const unsigned short* gpa[4];
  const unsigned short* gpw[4];
  int lof[4];
#pragma unroll
  for (int r = 0; r < 4; ++r) {
    const int id = r * 512 + tid;
    const int row = id >> 3, cc = id & 7;
    gpa[r] = A + (bm + row) * lda + (cc ^ (row & 7)) * 8;
    gpw[r] = Wp + (long)row * ldw + (cc ^ (row & 7)) * 8;
    lof[r] = id * 8;
  }

#define STAGE256(buf, kt) do {                                                \
    _Pragma("unroll")                                                         \
    for (int r = 0; r < 4; ++r) GLDS16(gpa[r] + (kt), lAs + (buf) * TBUF + lof[r]); \
    _Pragma("unroll")                                                         \
    for (int r = 0; r < 4; ++r) GLDS16(gpw[r] + (kt), lWs + (buf) * TBUF + lof[r]); \
  } while (0)

  f32x4 acc[8][4] = {};
  STAGE256(0, 0);
  __syncthreads();
  const int NT = K >> 6;
  for (int it = 0; it < NT; ++it) {
    const int cur = it & 1;
    if (it + 1 < NT) STAGE256(cur ^ 1, (it + 1) << 6);   // prefetch next K-tile

    bf16x8 bfr[4][2];
#pragma unroll
    for (int ni = 0; ni < 4; ++ni)
#pragma unroll
      for (int ks = 0; ks < 2; ++ks) {
        const int row = wc + ni * 16 + fr;
        const int ch  = (ks * 4 + q2) ^ (row & 7);
        bfr[ni][ks] = *(const bf16x8*)&Ws[cur * TBUF + row * 64 + ch * 8];
      }
    {
      bf16x8 af[8];
#pragma unroll
      for (int mi = 0; mi < 8; ++mi) {
        const int row = wr + mi * 16 + fr;
        const int ch  = q2 ^ (row & 7);                   // ks = 0
        af[mi] = *(const bf16x8*)&As[cur * TBUF + row * 64 + ch * 8];
      }
      __builtin_amdgcn_s_setprio(1);
#pragma unroll
      for (int mi = 0; mi < 8; ++mi)
#pragma unroll
        for (int ni = 0; ni < 4; ++ni)
          acc[mi][ni] = __builtin_amdgcn_mfma_f32_16x16x32_bf16(af[mi], bfr[ni][0], acc[mi][ni], 0, 0, 0);
      __builtin_amdgcn_s_setprio(0);
    }
    {
      bf16x8 af[8];
#pragma unroll
      for (int mi = 0; mi < 8; ++mi) {
        const int row = wr + mi * 16 + fr;
        const int ch  = (4 + q2) ^ (row & 7);             // ks = 1
        af[mi] = *(const bf16x8*)&As[cur * TBUF + row * 64 + ch * 8];
      }
      __builtin_amdgcn_s_setprio(1);
#pragma unroll
      for (int mi = 0; mi < 8; ++mi)
#pragma unroll
        for (int ni = 0; ni < 4; ++ni)
          acc[mi][ni] = __builtin_amdgcn_mfma_f32_16x16x32_bf16(af[mi], bfr[ni][1], acc[mi][ni], 0, 0, 0);
      __builtin_amdgcn_s_setprio(0);
    }
    __syncthreads();                  // cur reads done + prefetch drained
  }
#undef STAGE256

  const int q = lane >> 4;
#pragma unroll
  for (int ni = 0; ni < 4; ++ni) {
    const int col = wc + ni * 16 + fr;
    const float bv = biasp[col];
#pragma unroll
    for (int mi = 0; mi < 8; ++mi) {
      const long row = bm + wr + mi * 16 + q * 4;
#pragma unroll
      for (int j = 0; j < 4; ++j) {
        const float v = acc[mi][ni][j] + bv;
        if (mode == 0)      ((float*)Cp)[(row + j) * ldc + col] = v;
        else if (mode == 1) ((float*)Cp)[(row + j) * ldc + col] = tanhf(v);
        else if (mode == 2) ((float*)Cp)[(row + j) * ldc + col] = tanhf(v) + addp[(row + j) * ldadd + col];
        else                ((unsigned short*)Cp)[(row + j) * ldc + col] = f2bf(v);
      }
    }
  }
}

// ---------------------------------------------------------------------------
// Old 128-class core (r6): kept ONLY for the small-N o2 head (64x64 tiles).
// ---------------------------------------------------------------------------
template<int BM, int BN, int WM, int WN, int GN>
__device__ __forceinline__ void gemm_core(
    const unsigned short* __restrict__ A, long lda, long bm,
    const unsigned short* __restrict__ Wp, long ldw, int K,
    const float* __restrict__ biasp,
    void* __restrict__ Cp, long ldc,
    const float* __restrict__ addp, long ldadd, int mode)
{
  constexpr int ABUF = BM * 64;
  constexpr int WBUF = BN * 64;
  constexpr int AR = (BM * 8) / 256;
  constexpr int WR = (BN * 8) / 256;
  __shared__ __attribute__((aligned(16))) unsigned short sm[2 * (ABUF + WBUF)];
  unsigned short* As = sm;
  unsigned short* Ws = sm + 2 * ABUF;
  __attribute__((address_space(3))) unsigned short* lAs =
      (__attribute__((address_space(3))) unsigned short*)As;
  __attribute__((address_space(3))) unsigned short* lWs =
      (__attribute__((address_space(3))) unsigned short*)Ws;

  const int tid  = threadIdx.x;
  const int lane = tid & 63;
  const int wid  = tid >> 6;
  const int wr = (wid / GN) * (WM * 16);
  const int wc = (wid % GN) * (WN * 16);
  const int fr = lane & 15;
  const int q2 = lane >> 4;

  const unsigned short* gpa[AR];
  const unsigned short* gpw[WR];
  int lofa[AR], lofw[WR];
#pragma unroll
  for (int r = 0; r < AR; ++r) {
    const int id = r * 256 + tid;
    const int row = id >> 3, cc = id & 7;
    gpa[r] = A + (bm + row) * lda + (cc ^ (row & 7)) * 8;
    lofa[r] = id * 8;
  }
#pragma unroll
  for (int r = 0; r < WR; ++r) {
    const int id = r * 256 + tid;
    const int row = id >> 3, cc = id & 7;
    gpw[r] = Wp + (long)row * ldw + (cc ^ (row & 7)) * 8;
    lofw[r] = id * 8;
  }

#define STAGE(buf, kt) do {                                                   \
    _Pragma("unroll")                                                         \
    for (int r = 0; r < AR; ++r) GLDS16(gpa[r] + (kt), lAs + (buf) * ABUF + lofa[r]); \
    _Pragma("unroll")                                                         \
    for (int r = 0; r < WR; ++r) GLDS16(gpw[r] + (kt), lWs + (buf) * WBUF + lofw[r]); \
  } while (0)

  f32x4 acc[WM][WN] = {};
  STAGE(0, 0);
  __syncthreads();
  const int NK = K >> 6;
  for (int it = 0; it < NK; ++it) {
    const int cur = it & 1;
    if (it + 1 < NK) STAGE(cur ^ 1, (it + 1) << 6);
#pragma unroll
    for (int ks = 0; ks < 2; ++ks) {
      bf16x8 af[WM], wf[WN];
#pragma unroll
      for (int i = 0; i < WM; ++i) {
        const int row = wr + i * 16 + fr;
        const int ch  = (ks * 4 + q2) ^ (row & 7);
        af[i] = *(const bf16x8*)&As[cur * ABUF + row * 64 + ch * 8];
      }
#pragma unroll
      for (int i = 0; i < WN; ++i) {
        const int row = wc + i * 16 + fr;
        const int ch  = (ks * 4 + q2) ^ (row & 7);
        wf[i] = *(const bf16x8*)&Ws[cur * WBUF + row * 64 + ch * 8];
      }
#pragma unroll
      for (int mi = 0; mi < WM; ++mi)
#pragma unroll
        for (int ni = 0; ni < WN; ++ni)
          acc[mi][ni] = __builtin_amdgcn_mfma_f32_16x16x32_bf16(af[mi], wf[ni], acc[mi][ni], 0, 0, 0);
    }
    __syncthreads();
  }
#undef STAGE

  const int q = lane >> 4;
#pragma unroll
  for (int ni = 0; ni < WN; ++ni) {
    const int col = wc + ni * 16 + fr;
    const float bv = biasp[col];
#pragma unroll
    for (int mi = 0; mi < WM; ++mi) {
      const long row = bm + wr + mi * 16 + q * 4;
#pragma unroll
      for (int j = 0; j < 4; ++j) {
        const float v = acc[mi][ni][j] + bv;
        if (mode == 0)      ((float*)Cp)[(row + j) * ldc + col] = v;
        else if (mode == 1) ((float*)Cp)[(row + j) * ldc + col] = tanhf(v);
        else if (mode == 2) ((float*)Cp)[(row + j) * ldc + col] = tanhf(v) + addp[(row + j) * ldadd + col];
        else                ((unsigned short*)Cp)[(row + j) * ldc + col] = f2bf(v);
      }
    }
  }
}

// gi1 (bf16 out): 192 blocks (16 x 12), K=512, A row-stride T*INF.
__global__ __launch_bounds__(512, 2)
void k_gi1(const unsigned short* __restrict__ A,
           const unsigned short* __restrict__ W, const float* __restrict__ bias,
           unsigned short* __restrict__ C)
{
  const int wg = xcd_swz(blockIdx.x, gridDim.x);
  const int bx = wg & 15, by = wg >> 4;
  gemm256_core(A, (long)TT * INF, (long)bx * 256, W + (long)by * 256 * INF, INF, INF,
               bias + by * 256, C + by * 256, G3, nullptr, 0, 3);
}

// gh1 = h1 @ Whh1^T and gh2 = h2 @ Whh2^T, 384 blocks (16 x 12 x 2), bf16 out.
__global__ __launch_bounds__(512, 2)
void k_gh_dual(const unsigned short* __restrict__ h1b, const unsigned short* __restrict__ h2b,
               const unsigned short* __restrict__ W1, const unsigned short* __restrict__ W2,
               const float* __restrict__ b1, const float* __restrict__ b2,
               unsigned short* __restrict__ gh1, unsigned short* __restrict__ gh2)
{
  const int wg = xcd_swz(blockIdx.x, gridDim.x);   // 384
  const int bx = wg & 15;
  const int r  = wg >> 4;                          // 0..23
  const int z  = r >= 12;
  const int by = z ? r - 12 : r;
  const unsigned short* Aa = z ? h2b : h1b;
  const unsigned short* Ww = (z ? W2 : W1) + (long)by * 256 * HH;
  const float* bias = (z ? b2 : b1) + by * 256;
  unsigned short* C = (z ? gh2 : gh1) + by * 256;
  gemm256_core(Aa, HH, (long)bx * 256, Ww, HH, HH, bias, C, G3, nullptr, 0, 3);
}

// gi2 = h1 @ Wih2^T (bf16) | o1t = tanh(h1 @ Wo1^T + bo1) (f32). 224 blocks.
__global__ __launch_bounds__(512, 2)
void k_gi2_o1(const unsigned short* __restrict__ h1b,
              const unsigned short* __restrict__ Wih2, const float* __restrict__ bih2,
              unsigned short* __restrict__ gi2,
              const unsigned short* __restrict__ Wo1, const float* __restrict__ bo1,
              float* __restrict__ o1t)
{
  const int wg = xcd_swz(blockIdx.x, gridDim.x);   // 224
  const bool g = (wg < 192);
  const int idx = g ? wg : wg - 192;
  const int bx = idx & 15;
  const int by = idx >> 4;                         // g: 0..11, else 0..1
  const unsigned short* Ww = g ? (Wih2 + (long)by * 256 * HH) : (Wo1 + (long)by * 256 * HH);
  const float* bias        = g ? (bih2 + by * 256)            : (bo1 + by * 256);
  void* C                  = g ? (void*)(gi2 + by * 256)      : (void*)(o1t + by * 256);
  const long ldc           = g ? (long)G3 : (long)OUTF;
  gemm256_core(h1b, HH, (long)bx * 256, Ww, HH, HH, bias, C, ldc,
               nullptr, 0, g ? 3 : 1);
}

// out[b,t,:] = tanh(h2 @ Wo2^T + bo2) + o1t   (64x64 tiles, 512 blocks)
__global__ __launch_bounds__(256)
void k_o2_out(const unsigned short* __restrict__ h2b,
              const unsigned short* __restrict__ Wo2, const float* __restrict__ bo2,
              const float* __restrict__ o1t, float* __restrict__ outp)
{
  const int wg = xcd_swz(blockIdx.x, gridDim.x);   // 512
  const int bx = wg % 64;
  const int by = wg / 64;
  gemm_core<64,64,2,2,2>(h2b, HH, (long)bx * 64, Wo2 + (long)by * 64 * HH, HH, HH,
                         bo2 + by * 64, outp + by * 64, (long)TT * OUTF,
                         o1t + by * 64, OUTF, 2);
}

// GRU gate: h = (1-z)*n + z*h_old. gi, gh bf16; recurrence on bf16 hb.
__global__ __launch_bounds__(256)
void k_gate(const unsigned short* __restrict__ gi, long gistride,
            const unsigned short* __restrict__ gh,
            unsigned short* __restrict__ hb,
            float* __restrict__ auxp)
{
  const int i4 = blockIdx.x * 256 + threadIdx.x;
  const int e  = i4 << 2;
  const int b = e >> 10;                  // H = 1024
  const int c = e & 1023;
  const unsigned short* g = gi + (long)b * gistride + c;
  const ushort4 a0 = *(const ushort4*)(g);
  const ushort4 a1 = *(const ushort4*)(g + HH);
  const ushort4 a2 = *(const ushort4*)(g + 2 * HH);
  const unsigned short* gg = gh + (long)b * G3 + c;
  const ushort4 b0 = *(const ushort4*)(gg);
  const ushort4 b1 = *(const ushort4*)(gg + HH);
  const ushort4 b2 = *(const ushort4*)(gg + 2 * HH);
  const f32x4 ir  = f32x4{bf2f(a0.x), bf2f(a0.y), bf2f(a0.z), bf2f(a0.w)};
  const f32x4 iz  = f32x4{bf2f(a1.x), bf2f(a1.y), bf2f(a1.z), bf2f(a1.w)};
  const f32x4 inn = f32x4{bf2f(a2.x), bf2f(a2.y), bf2f(a2.z), bf2f(a2.w)};
  const f32x4 hr  = f32x4{bf2f(b0.x), bf2f(b0.y), bf2f(b0.z), bf2f(b0.w)};
  const f32x4 hz  = f32x4{bf2f(b1.x), bf2f(b1.y), bf2f(b1.z), bf2f(b1.w)};
  const f32x4 hn  = f32x4{bf2f(b2.x), bf2f(b2.y), bf2f(b2.z), bf2f(b2.w)};
  const ushort4 ho = *(const ushort4*)(hb + e);
  const f32x4 h = f32x4{bf2f(ho.x), bf2f(ho.y), bf2f(ho.z), bf2f(ho.w)};
  f32x4 hnew;
  float vsum = 0.f;
#pragma unroll
  for (int j = 0; j < 4; ++j) {
    const float r = 1.f / (1.f + __expf(-(ir[j] + hr[j])));
    const float z = 1.f / (1.f + __expf(-(iz[j] + hz[j])));
    const float n = tanhf(inn[j] + r * hn[j]);
    hnew[j] = (1.f - z) * n + z * h[j];
    vsum += hnew[j] * hnew[j];
  }
  ushort4 o;
  o.x = f2bf(hnew[0]); o.y = f2bf(hnew[1]); o.z = f2bf(hnew[2]); o.w = f2bf(hnew[3]);
  *(ushort4*)(hb + e) = o;
  if (auxp != nullptr) {
#pragma unroll
    for (int off = 32; off > 0; off >>= 1) vsum += __shfl_down(vsum, off);
    __shared__ float wsum[4];
    if ((threadIdx.x & 63) == 0) wsum[threadIdx.x >> 6] = vsum;
    __syncthreads();
    if (threadIdx.x == 0) auxp[blockIdx.x] = wsum[0] + wsum[1] + wsum[2] + wsum[3];
  }
}

__global__ __launch_bounds__(256)
void aux_reduce(const float* __restrict__ p, int n, float* __restrict__ out, float scale) {
  float s = 0.f;
  for (int i = threadIdx.x; i < n; i += 256) s += p[i];
#pragma unroll
  for (int off = 32; off > 0; off >>= 1) s += __shfl_down(s, off);
  __shared__ float wsum[4];
  if ((threadIdx.x & 63) == 0) wsum[threadIdx.x >> 6] = s;
  __syncthreads();
  if (threadIdx.x == 0) out[0] = (wsum[0] + wsum[1] + wsum[2] + wsum[3]) * scale;
}

extern "C" void kernel_launch(void* const* d_in, const int* in_sizes, int n_in,
                              void* d_out, int out_size, void* d_ws, size_t ws_size,
                              hipStream_t stream) {
  const float* x    = (const float*)d_in[0];
  const float* Wih1 = (const float*)d_in[1];
  const float* Whh1 = (const float*)d_in[2];
  const float* bih1 = (const float*)d_in[3];
  const float* bhh1 = (const float*)d_in[4];
  const float* Wih2 = (const float*)d_in[5];
  const float* Whh2 = (const float*)d_in[6];
  const float* bih2 = (const float*)d_in[7];
  const float* bhh2 = (const float*)d_in[8];
  const float* Wo1  = (const float*)d_in[9];
  const float* bo1  = (const float*)d_in[10];
  const float* Wo2  = (const float*)d_in[11];
  const float* bo2  = (const float*)d_in[12];

  char* ws = (char*)d_ws;
  size_t off = 0;
  auto alloc = [&](size_t bytes) {
    char* p = ws + off;
    off = (off + bytes + 255) & ~(size_t)255;
    return p;
  };

  unsigned short* xb    = (unsigned short*)alloc((size_t)BB * TT * INF * 2);
  unsigned short* wih1b = (unsigned short*)alloc((size_t)G3 * INF * 2);
  unsigned short* whh1b = (unsigned short*)alloc((size_t)G3 * HH * 2);
  unsigned short* wih2b = (unsigned short*)alloc((size_t)G3 * HH * 2);
  unsigned short* whh2b = (unsigned short*)alloc((size_t)G3 * HH * 2);
  unsigned short* wo1b  = (unsigned short*)alloc((size_t)OUTF * HH * 2);
  unsigned short* wo2b  = (unsigned short*)alloc((size_t)OUTF * HH * 2);
  unsigned short* h1b = (unsigned short*)alloc((size_t)BB * HH * 2);
  unsigned short* h2b = (unsigned short*)alloc((size_t)BB * HH * 2);
  unsigned short* gh1 = (unsigned short*)alloc((size_t)BB * G3 * 2);  // also gi2
  unsigned short* gh2 = (unsigned short*)alloc((size_t)BB * G3 * 2);
  unsigned short* gi1b = (unsigned short*)alloc((size_t)BB * G3 * 2);
  float* o1t  = (float*)alloc((size_t)BB * OUTF * 4);
  float* auxp = (float*)alloc((size_t)TT * (BB * HH / 1024) * 4);
  unsigned short* gi2 = gh1;          // gh1 dead after gate1; stream order safe

  float* aux = (float*)d_out + (size_t)BB * TT * OUTF;

  auto cvt = [&](const float* src, unsigned short* dst, size_t n) {
    int n4 = (int)(n / 4);
    cvt_f32_to_bf16_x4<<<dim3((n4 + 255) / 256), dim3(256), 0, stream>>>(src, dst, n4);
  };
  cvt(x,    xb,    (size_t)BB * TT * INF);
  cvt(Wih1, wih1b, (size_t)G3 * INF);
  cvt(Whh1, whh1b, (size_t)G3 * HH);
  cvt(Wih2, wih2b, (size_t)G3 * HH);
  cvt(Whh2, whh2b, (size_t)G3 * HH);
  cvt(Wo1,  wo1b,  (size_t)OUTF * HH);
  cvt(Wo2,  wo2b,  (size_t)OUTF * HH);

  hipMemsetAsync(h1b, 0, (size_t)BB * HH * 2, stream);
  hipMemsetAsync(h2b, 0, (size_t)BB * HH * 2, stream);

  const dim3 blk(256);
  const dim3 blk512(512);
  const int gateGrid = BB * HH / 1024;   // 4096

  for (int t = 0; t < TT; ++t) {
    k_gi1<<<dim3(192), blk512, 0, stream>>>(xb + (size_t)t * INF, wih1b, bih1, gi1b);
    k_gh_dual<<<dim3(384), blk512, 0, stream>>>(h1b, h2b, whh1b, whh2b, bhh1, bhh2, gh1, gh2);
    k_gate<<<dim3(gateGrid), blk, 0, stream>>>(gi1b, (long)G3, gh1, h1b, nullptr);
    k_gi2_o1<<<dim3(224), blk512, 0, stream>>>(h1b, wih2b, bih2, gi2, wo1b, bo1, o1t);
    k_gate<<<dim3(gateGrid), blk, 0, stream>>>(gi2, (long)G3, gh2, h2b,
                                               auxp + (size_t)t * gateGrid);
    k_o2_out<<<dim3(512), blk, 0, stream>>>(h2b, wo2b, bo2, o1t,
                                            (float*)d_out + (size_t)t * OUTF);
  }
  aux_reduce<<<dim3(1), blk, 0, stream>>>(auxp, TT * gateGrid, aux,
                                          1.f / ((float)BB * (float)HH));
}

// Round 9
// 1657.436 us; speedup vs baseline: 1.1349x; 1.0015x over previous
//
#include <hip/hip_runtime.h>
#include <cstdint>

#define BB   4096
#define TT   7
#define INF  512
#define HH   1024
#define OUTF 512
#define G3   3072   // 3*H

typedef short bf16x8 __attribute__((ext_vector_type(8)));
typedef float f32x4  __attribute__((ext_vector_type(4)));

static __device__ __forceinline__ unsigned short f2bf(float f) {
  unsigned u = __float_as_uint(f);
  unsigned r = ((u >> 16) & 1u) + 0x7FFFu;   // RNE
  return (unsigned short)((u + r) >> 16);
}
static __device__ __forceinline__ float bf2f(unsigned short s) {
  return __uint_as_float(((unsigned)s) << 16);
}

#define GLDS16(gp, lp)                                                        \
  __builtin_amdgcn_global_load_lds(                                           \
      (const __attribute__((address_space(1))) void*)(gp),                    \
      (__attribute__((address_space(3))) void*)(lp), 16, 0, 0)

__device__ __forceinline__ int xcd_swz(int bid, int nwg) {
  return (bid & 7) * (nwg >> 3) + (bid >> 3);   // bijective: nwg % 8 == 0
}

__global__ __launch_bounds__(256)
void cvt_f32_to_bf16_x4(const float* __restrict__ in, unsigned short* __restrict__ out, int n4) {
  int i = blockIdx.x * 256 + threadIdx.x;
  if (i >= n4) return;
  const float4 v = ((const float4*)in)[i];
  ushort4 o;
  o.x = f2bf(v.x); o.y = f2bf(v.y); o.z = f2bf(v.z); o.w = f2bf(v.w);
  ((ushort4*)out)[i] = o;
}

// ---------------------------------------------------------------------------
// GEMM core (r5-proven): C[M,N] = A[M,K] @ W[N,K]^T + bias. bf16 in, f32 acc.
// 128x128 tile, BK=64, single-buffered, 32 KB LDS (~5 blocks/CU -> TLP hides
// staging latency; measured equal to 64KB dbuf at same shape, more occupancy).
// Chunk-XOR swizzle (0 bank conflicts measured): LDS dest LINEAR (m104);
// global source chunk cc^(row&7); same involution on ds_read.
// mode: 0 = f32 store; 1 = f32 tanh; 2 = f32 tanh + add[]; 3 = bf16 store.
// NOTE: exactly ONE gemm_core call per kernel (single 32KB __shared__).
// ---------------------------------------------------------------------------
__device__ __forceinline__ void gemm_core128(
    const unsigned short* __restrict__ A, long lda, long bm,
    const unsigned short* __restrict__ Wp, long ldw, int K,
    const float* __restrict__ biasp,
    void* __restrict__ Cp, long ldc,
    const float* __restrict__ addp, long ldadd, int mode)
{
  __shared__ __attribute__((aligned(16))) unsigned short sm[256 * 64];  // 32 KB
  unsigned short* As = sm;             // [128][64]
  unsigned short* Ws = sm + 128 * 64;
  __attribute__((address_space(3))) unsigned short* lAs =
      (__attribute__((address_space(3))) unsigned short*)As;
  __attribute__((address_space(3))) unsigned short* lWs =
      (__attribute__((address_space(3))) unsigned short*)Ws;

  const int tid  = threadIdx.x;
  const int lane = tid & 63;
  const int wid  = tid >> 6;
  const int wr = (wid >> 1) * 64;
  const int wc = (wid & 1) * 64;
  const int fr = lane & 15;
  const int q2 = lane >> 4;           // 0..3: 16B k-chunk within 32-wide K-slice

  // staging: id = r*256+tid; row = id>>3, cc = id&7 (16B chunk in row);
  // LDS dest linear at id*16B; global source chunk = cc ^ (row&7).
  const unsigned short* gpa[4];
  const unsigned short* gpw[4];
  int lof[4];
#pragma unroll
  for (int r = 0; r < 4; ++r) {
    const int id = r * 256 + tid;
    const int row = id >> 3, cc = id & 7;
    gpa[r] = A + (bm + row) * lda + (cc ^ (row & 7)) * 8;
    gpw[r] = Wp + (long)row * ldw + (cc ^ (row & 7)) * 8;
    lof[r] = id * 8;                  // elements (=16B*id)
  }

  f32x4 acc[4][4] = {};
  for (int kt = 0; kt < K; kt += 64) {
    if (kt) __syncthreads();          // prior reads done before overwrite
#pragma unroll
    for (int r = 0; r < 4; ++r) GLDS16(gpa[r] + kt, lAs + lof[r]);
#pragma unroll
    for (int r = 0; r < 4; ++r) GLDS16(gpw[r] + kt, lWs + lof[r]);
    __syncthreads();                  // compiler drains vmcnt before s_barrier

#pragma unroll
    for (int ks = 0; ks < 2; ++ks) {
      bf16x8 af[4], wf[4];
#pragma unroll
      for (int i = 0; i < 4; ++i) {
        const int row = wr + i * 16 + fr;
        const int ch  = (ks * 4 + q2) ^ (row & 7);
        af[i] = *(const bf16x8*)&As[row * 64 + ch * 8];
      }
#pragma unroll
      for (int i = 0; i < 4; ++i) {
        const int row = wc + i * 16 + fr;
        const int ch  = (ks * 4 + q2) ^ (row & 7);
        wf[i] = *(const bf16x8*)&Ws[row * 64 + ch * 8];
      }
#pragma unroll
      for (int mi = 0; mi < 4; ++mi)
#pragma unroll
        for (int ni = 0; ni < 4; ++ni)
          acc[mi][ni] = __builtin_amdgcn_mfma_f32_16x16x32_bf16(af[mi], wf[ni], acc[mi][ni], 0, 0, 0);
    }
  }

  const int q = lane >> 4;
#pragma unroll
  for (int ni = 0; ni < 4; ++ni) {
    const int col = wc + ni * 16 + fr;
    const float bv = biasp[col];
#pragma unroll
    for (int mi = 0; mi < 4; ++mi) {
      const long row = bm + wr + mi * 16 + q * 4;
#pragma unroll
      for (int j = 0; j < 4; ++j) {
        const float v = acc[mi][ni][j] + bv;
        if (mode == 0)      ((float*)Cp)[(row + j) * ldc + col] = v;
        else if (mode == 1) ((float*)Cp)[(row + j) * ldc + col] = tanhf(v);
        else if (mode == 2) ((float*)Cp)[(row + j) * ldc + col] = tanhf(v) + addp[(row + j) * ldadd + col];
        else                ((unsigned short*)Cp)[(row + j) * ldc + col] = f2bf(v);
      }
    }
  }
}

// ---------------------------------------------------------------------------
// D1: everything depending only on state (t-1), one dispatch for fill:
//   [0,1536)     gh1/gh2 = h1/h2 @ Whh^T (K=1024, bf16)  -- long K first
//   [1536,2304)  gi1 = x_t @ Wih1^T      (K=512,  bf16)
//   [2304,2432)  out(t-1) = tanh(h2@Wo2^T+bo2) + o1t     (t>0 only)
// ---------------------------------------------------------------------------
__global__ __launch_bounds__(256)
void k_d1(const unsigned short* __restrict__ xb_t,
          const unsigned short* __restrict__ wih1b, const float* __restrict__ bih1,
          unsigned short* __restrict__ gi1b,
          const unsigned short* __restrict__ h1b, const unsigned short* __restrict__ h2b,
          const unsigned short* __restrict__ whh1b, const unsigned short* __restrict__ whh2b,
          const float* __restrict__ bhh1, const float* __restrict__ bhh2,
          unsigned short* __restrict__ gh1, unsigned short* __restrict__ gh2,
          const unsigned short* __restrict__ wo2b, const float* __restrict__ bo2,
          const float* __restrict__ o1t_prev, float* __restrict__ out_prev)
{
  const int wg = xcd_swz(blockIdx.x, gridDim.x);
  const unsigned short* A; long lda; long bm;
  const unsigned short* W; int K;
  const float* bias; void* C; long ldc; int mode;
  const float* addp = nullptr; long ldadd = 0;
  if (wg < 1536) {                      // gh1 / gh2
    const int z = wg >= 768;
    const int idx = z ? wg - 768 : wg;
    const int bx = idx & 31, by = idx >> 5;
    A = z ? h2b : h1b; lda = HH; bm = (long)bx * 128;
    W = (z ? whh2b : whh1b) + (long)by * 128 * HH; K = HH;
    bias = (z ? bhh2 : bhh1) + by * 128;
    C = (z ? gh2 : gh1) + by * 128; ldc = G3; mode = 3;
  } else if (wg < 2304) {               // gi1
    const int idx = wg - 1536;
    const int bx = idx & 31, by = idx >> 5;
    A = xb_t; lda = (long)TT * INF; bm = (long)bx * 128;
    W = wih1b + (long)by * 128 * INF; K = INF;
    bias = bih1 + by * 128; C = gi1b + by * 128; ldc = G3; mode = 3;
  } else {                              // o2 -> d_out row t-1
    const int idx = wg - 2304;
    const int bx = idx & 31, by = idx >> 5;   // by 0..3
    A = h2b; lda = HH; bm = (long)bx * 128;
    W = wo2b + (long)by * 128 * HH; K = HH;
    bias = bo2 + by * 128;
    C = out_prev + by * 128; ldc = (long)TT * OUTF; mode = 2;
    addp = o1t_prev + by * 128; ldadd = OUTF;
  }
  gemm_core128(A, lda, bm, W, (long)K, K, bias, C, ldc, addp, ldadd, mode);
}

// D2: gi2 = h1 @ Wih2^T (bf16) | o1t = tanh(h1 @ Wo1^T + bo1) (f32). 896 blocks.
__global__ __launch_bounds__(256)
void k_gi2_o1(const unsigned short* __restrict__ h1b,
              const unsigned short* __restrict__ Wih2, const float* __restrict__ bih2,
              unsigned short* __restrict__ gi2,
              const unsigned short* __restrict__ Wo1, const float* __restrict__ bo1,
              float* __restrict__ o1t)
{
  const int wg = xcd_swz(blockIdx.x, gridDim.x);   // 896
  const bool g = (wg < 768);
  const int idx = g ? wg : wg - 768;
  const int bx = idx & 31;
  const int by = idx >> 5;                         // g: 0..23, else 0..3
  const unsigned short* Ww = g ? (Wih2 + (long)by * 128 * HH) : (Wo1 + (long)by * 128 * HH);
  const float* bias        = g ? (bih2 + by * 128)            : (bo1 + by * 128);
  void* C                  = g ? (void*)(gi2 + by * 128)      : (void*)(o1t + by * 128);
  const long ldc           = g ? (long)G3 : (long)OUTF;
  gemm_core128(h1b, HH, (long)bx * 128, Ww, HH, HH, bias, C, ldc,
               nullptr, 0, g ? 3 : 1);
}

// final step's output head (128 blocks, mode 2)
__global__ __launch_bounds__(256)
void k_o2f(const unsigned short* __restrict__ h2b,
           const unsigned short* __restrict__ Wo2, const float* __restrict__ bo2,
           const float* __restrict__ o1t, float* __restrict__ outp)
{
  const int wg = xcd_swz(blockIdx.x, gridDim.x);   // 128
  const int bx = wg & 31;
  const int by = wg >> 5;
  gemm_core128(h2b, HH, (long)bx * 128, Wo2 + (long)by * 128 * HH, HH, HH,
               bo2 + by * 128, outp + by * 128, (long)TT * OUTF,
               o1t + by * 128, OUTF, 2);
}

// GRU gate: h = (1-z)*n + z*h_old. gi, gh bf16; recurrence on bf16 hb.
__global__ __launch_bounds__(256)
void k_gate(const unsigned short* __restrict__ gi,
            const unsigned short* __restrict__ gh,
            unsigned short* __restrict__ hb,
            float* __restrict__ auxp)
{
  const int i4 = blockIdx.x * 256 + threadIdx.x;
  const int e  = i4 << 2;
  const int b = e >> 10;                  // H = 1024
  const int c = e & 1023;
  const unsigned short* g = gi + (long)b * G3 + c;
  const ushort4 a0 = *(const ushort4*)(g);
  const ushort4 a1 = *(const ushort4*)(g + HH);
  const ushort4 a2 = *(const ushort4*)(g + 2 * HH);
  const unsigned short* gg = gh + (long)b * G3 + c;
  const ushort4 b0 = *(const ushort4*)(gg);
  const ushort4 b1 = *(const ushort4*)(gg + HH);
  const ushort4 b2 = *(const ushort4*)(gg + 2 * HH);
  const f32x4 ir  = f32x4{bf2f(a0.x), bf2f(a0.y), bf2f(a0.z), bf2f(a0.w)};
  const f32x4 iz  = f32x4{bf2f(a1.x), bf2f(a1.y), bf2f(a1.z), bf2f(a1.w)};
  const f32x4 inn = f32x4{bf2f(a2.x), bf2f(a2.y), bf2f(a2.z), bf2f(a2.w)};
  const f32x4 hr  = f32x4{bf2f(b0.x), bf2f(b0.y), bf2f(b0.z), bf2f(b0.w)};
  const f32x4 hz  = f32x4{bf2f(b1.x), bf2f(b1.y), bf2f(b1.z), bf2f(b1.w)};
  const f32x4 hn  = f32x4{bf2f(b2.x), bf2f(b2.y), bf2f(b2.z), bf2f(b2.w)};
  const ushort4 ho = *(const ushort4*)(hb + e);
  const f32x4 h = f32x4{bf2f(ho.x), bf2f(ho.y), bf2f(ho.z), bf2f(ho.w)};
  f32x4 hnew;
  float vsum = 0.f;
#pragma unroll
  for (int j = 0; j < 4; ++j) {
    const float r = 1.f / (1.f + __expf(-(ir[j] + hr[j])));
    const float z = 1.f / (1.f + __expf(-(iz[j] + hz[j])));
    const float n = tanhf(inn[j] + r * hn[j]);
    hnew[j] = (1.f - z) * n + z * h[j];
    vsum += hnew[j] * hnew[j];
  }
  ushort4 o;
  o.x = f2bf(hnew[0]); o.y = f2bf(hnew[1]); o.z = f2bf(hnew[2]); o.w = f2bf(hnew[3]);
  *(ushort4*)(hb + e) = o;
  if (auxp != nullptr) {
#pragma unroll
    for (int off = 32; off > 0; off >>= 1) vsum += __shfl_down(vsum, off);
    __shared__ float wsum[4];
    if ((threadIdx.x & 63) == 0) wsum[threadIdx.x >> 6] = vsum;
    __syncthreads();
    if (threadIdx.x == 0) auxp[blockIdx.x] = wsum[0] + wsum[1] + wsum[2] + wsum[3];
  }
}

__global__ __launch_bounds__(256)
void aux_reduce(const float* __restrict__ p, int n, float* __restrict__ out, float scale) {
  float s = 0.f;
  for (int i = threadIdx.x; i < n; i += 256) s += p[i];
#pragma unroll
  for (int off = 32; off > 0; off >>= 1) s += __shfl_down(s, off);
  __shared__ float wsum[4];
  if ((threadIdx.x & 63) == 0) wsum[threadIdx.x >> 6] = s;
  __syncthreads();
  if (threadIdx.x == 0) out[0] = (wsum[0] + wsum[1] + wsum[2] + wsum[3]) * scale;
}

extern "C" void kernel_launch(void* const* d_in, const int* in_sizes, int n_in,
                              void* d_out, int out_size, void* d_ws, size_t ws_size,
                              hipStream_t stream) {
  const float* x    = (const float*)d_in[0];
  const float* Wih1 = (const float*)d_in[1];
  const float* Whh1 = (const float*)d_in[2];
  const float* bih1 = (const float*)d_in[3];
  const float* bhh1 = (const float*)d_in[4];
  const float* Wih2 = (const float*)d_in[5];
  const float* Whh2 = (const float*)d_in[6];
  const float* bih2 = (const float*)d_in[7];
  const float* bhh2 = (const float*)d_in[8];
  const float* Wo1  = (const float*)d_in[9];
  const float* bo1  = (const float*)d_in[10];
  const float* Wo2  = (const float*)d_in[11];
  const float* bo2  = (const float*)d_in[12];

  char* ws = (char*)d_ws;
  size_t off = 0;
  auto alloc = [&](size_t bytes) {
    char* p = ws + off;
    off = (off + bytes + 255) & ~(size_t)255;
    return p;
  };

  unsigned short* xb    = (unsigned short*)alloc((size_t)BB * TT * INF * 2);
  unsigned short* wih1b = (unsigned short*)alloc((size_t)G3 * INF * 2);
  unsigned short* whh1b = (unsigned short*)alloc((size_t)G3 * HH * 2);
  unsigned short* wih2b = (unsigned short*)alloc((size_t)G3 * HH * 2);
  unsigned short* whh2b = (unsigned short*)alloc((size_t)G3 * HH * 2);
  unsigned short* wo1b  = (unsigned short*)alloc((size_t)OUTF * HH * 2);
  unsigned short* wo2b  = (unsigned short*)alloc((size_t)OUTF * HH * 2);
  unsigned short* h1b = (unsigned short*)alloc((size_t)BB * HH * 2);
  unsigned short* h2b = (unsigned short*)alloc((size_t)BB * HH * 2);
  unsigned short* gh1 = (unsigned short*)alloc((size_t)BB * G3 * 2);  // also gi2
  unsigned short* gh2 = (unsigned short*)alloc((size_t)BB * G3 * 2);
  unsigned short* gi1b = (unsigned short*)alloc((size_t)BB * G3 * 2);
  float* o1t  = (float*)alloc((size_t)BB * OUTF * 4);
  float* auxp = (float*)alloc((size_t)TT * (BB * HH / 1024) * 4);
  unsigned short* gi2 = gh1;          // gh1 dead after gate1; stream order safe

  float* aux = (float*)d_out + (size_t)BB * TT * OUTF;

  auto cvt = [&](const float* src, unsigned short* dst, size_t n) {
    int n4 = (int)(n / 4);
    cvt_f32_to_bf16_x4<<<dim3((n4 + 255) / 256), dim3(256), 0, stream>>>(src, dst, n4);
  };
  cvt(x,    xb,    (size_t)BB * TT * INF);
  cvt(Wih1, wih1b, (size_t)G3 * INF);
  cvt(Whh1, whh1b, (size_t)G3 * HH);
  cvt(Wih2, wih2b, (size_t)G3 * HH);
  cvt(Whh2, whh2b, (size_t)G3 * HH);
  cvt(Wo1,  wo1b,  (size_t)OUTF * HH);
  cvt(Wo2,  wo2b,  (size_t)OUTF * HH);

  hipMemsetAsync(h1b, 0, (size_t)BB * HH * 2, stream);
  hipMemsetAsync(h2b, 0, (size_t)BB * HH * 2, stream);

  const dim3 blk(256);
  const int gateGrid = BB * HH / 1024;   // 4096

  for (int t = 0; t < TT; ++t) {
    const int d1grid = (t == 0) ? 2304 : 2432;   // o2 segment only when t > 0
    k_d1<<<dim3(d1grid), blk, 0, stream>>>(
        xb + (size_t)t * INF, wih1b, bih1, gi1b,
        h1b, h2b, whh1b, whh2b, bhh1, bhh2, gh1, gh2,
        wo2b, bo2, o1t, (float*)d_out + (size_t)(t > 0 ? t - 1 : 0) * OUTF);
    k_gate<<<dim3(gateGrid), blk, 0, stream>>>(gi1b, gh1, h1b, nullptr);
    k_gi2_o1<<<dim3(896), blk, 0, stream>>>(h1b, wih2b, bih2, gi2, wo1b, bo1, o1t);
    k_gate<<<dim3(gateGrid), blk, 0, stream>>>(gi2, gh2, h2b,
                                               auxp + (size_t)t * gateGrid);
  }
  k_o2f<<<dim3(128), blk, 0, stream>>>(h2b, wo2b, bo2, o1t,
                                       (float*)d_out + (size_t)(TT - 1) * OUTF);
  aux_reduce<<<dim3(1), blk, 0, stream>>>(auxp, TT * gateGrid, aux,
                                          1.f / ((float)BB * (float)HH));
}